// Round 7
// baseline (935.773 us; speedup 1.0000x reference)
//
#include <hip/hip_runtime.h>
#include <hip/hip_fp16.h>
#include <math.h>

#define HID   64
#define HEADS 4
#define DH    16
#define NU    30000
#define NE_   60000
#define NV    1000
#define NTOT  91000
#define ETOT  870000
#define NSLOT 541000
#define LAYERS 2
#define NCOLS 1856      // fused cols per layer: 832 (t0) + 832 (t1) + 192 (t2)

// Edge-type tables
__device__ const int d_EOFF[14] = {0,150000,270000,330000,370000,400000,450000,
                                   570000,630000,670000,700000,750000,810000,870000};
__device__ const int d_ECNT[13] = {150000,120000,60000,40000,30000,50000,
                                   120000,60000,40000,30000,50000,60000,60000};
__device__ const int d_EST[13]  = {0,0,0,0,0,0,1,1,1,1,1,1,2};
__device__ const int d_EDT[13]  = {0,1,1,1,1,1,0,0,0,0,0,2,1};
__device__ const int d_NOFF[3]  = {0, NU, NU + NE_};
// slot base per edge type in the kvt mega-table (src-node indexed per e)
__device__ const int d_EBASE[13] = {0,30000,60000,90000,120000,150000,
                                    180000,240000,300000,360000,420000,480000,540000};

struct EdgePtrs { const int* p[13]; };

typedef float f32x2 __attribute__((ext_vector_type(2)));

__device__ __forceinline__ void pk_fma(f32x2& acc, f32x2 a, f32x2 b) {
    asm("v_pk_fma_f32 %0, %1, %2, %0" : "+v"(acc) : "v"(a), "v"(b));
}
// a is wave-uniform (SGPR pair) -> VOP3P scalar source, no v_mov marshalling.
__device__ __forceinline__ void pk_fma_sv(f32x2& acc, f32x2 a_sgpr, f32x2 b) {
    asm("v_pk_fma_f32 %0, %1, %2, %0" : "+v"(acc) : "s"(a_sgpr), "v"(b));
}

__device__ __forceinline__ int node_type(int n) {
    return (n >= NU) + (n >= NU + NE_);
}

// ---------------- input projection: h = x@W + b + emb[ids] ----------------
__global__ __launch_bounds__(64)
void k_init(const float* __restrict__ xu, const float* __restrict__ xe,
            const float* __restrict__ xv,
            const float* __restrict__ Wu, const float* __restrict__ bu,
            const float* __restrict__ We, const float* __restrict__ be,
            const float* __restrict__ Wv_, const float* __restrict__ bv,
            const float* __restrict__ embu, const float* __restrict__ embe,
            const float* __restrict__ embv,
            const int* __restrict__ idu, const int* __restrict__ ide,
            const int* __restrict__ idv,
            float* __restrict__ h) {
    int n0 = blockIdx.x * 16;
    int t = node_type(n0);          // 16-node tiles never straddle type boundaries
    int j = threadIdx.x;            // output column 0..63
    const float *x, *W, *bb, *emb; const int* ids; int in_dim;
    if (t == 0)      { x = xu; W = Wu;  bb = bu; emb = embu; ids = idu; in_dim = 32; }
    else if (t == 1) { x = xe; W = We;  bb = be; emb = embe; ids = ide; in_dim = 32; }
    else             { x = xv; W = Wv_; bb = bv; emb = embv; ids = idv; in_dim = 16; }
    int nl = n0 - d_NOFF[t];
    int nn = min(16, NTOT - n0);
    __shared__ float xT[32][20];    // transposed x tile, +4 pad
    int ncs = (in_dim == 32) ? 3 : 2;       // log2 float4-chunks per node
    int nch = 1 << ncs;
    for (int idx = j; idx < (nch << 4); idx += 64) {
        int n = idx >> ncs, c = idx & (nch - 1);
        float4 v = make_float4(0.f, 0.f, 0.f, 0.f);
        if (n < nn) v = *(const float4*)(x + (size_t)(nl + n) * in_dim + c * 4);
        xT[c * 4 + 0][n] = v.x;
        xT[c * 4 + 1][n] = v.y;
        xT[c * 4 + 2][n] = v.z;
        xT[c * 4 + 3][n] = v.w;
    }
    __syncthreads();
    float bj = bb[j];
    f32x2 acc2[8];
    #pragma unroll
    for (int p = 0; p < 8; p++) {
        float ex = (2 * p     < nn) ? emb[(size_t)ids[nl + 2 * p    ] * 64 + j] : 0.f;
        float ey = (2 * p + 1 < nn) ? emb[(size_t)ids[nl + 2 * p + 1] * 64 + j] : 0.f;
        acc2[p].x = bj + ex; acc2[p].y = bj + ey;
    }
    if (in_dim == 32) {
        #pragma unroll
        for (int i = 0; i < 32; i++) {
            float w = W[i * 64 + j];
            f32x2 w2; w2.x = w; w2.y = w;
            #pragma unroll
            for (int qd = 0; qd < 4; qd++) {
                float4 hv = *(const float4*)(&xT[i][qd * 4]);
                f32x2 p0; p0.x = hv.x; p0.y = hv.y; pk_fma(acc2[2 * qd],     p0, w2);
                f32x2 p1; p1.x = hv.z; p1.y = hv.w; pk_fma(acc2[2 * qd + 1], p1, w2);
            }
        }
    } else {
        #pragma unroll
        for (int i = 0; i < 16; i++) {
            float w = W[i * 64 + j];
            f32x2 w2; w2.x = w; w2.y = w;
            #pragma unroll
            for (int qd = 0; qd < 4; qd++) {
                float4 hv = *(const float4*)(&xT[i][qd * 4]);
                f32x2 p0; p0.x = hv.x; p0.y = hv.y; pk_fma(acc2[2 * qd],     p0, w2);
                f32x2 p1; p1.x = hv.z; p1.y = hv.w; pk_fma(acc2[2 * qd + 1], p1, w2);
            }
        }
    }
    #pragma unroll
    for (int p = 0; p < 8; p++) {
        if (2 * p     < nn) h[(size_t)(n0 + 2 * p)     * 64 + j] = acc2[p].x;
        if (2 * p + 1 < nn) h[(size_t)(n0 + 2 * p + 1) * 64 + j] = acc2[p].y;
    }
}

// ---------------- CSR build (exact rows, entry = slot index) ----------------
__global__ void k_cnt(EdgePtrs ep, int* __restrict__ cnt) {
    int eidx = blockIdx.x * blockDim.x + threadIdx.x;
    if (eidx >= ETOT) return;
    int e = 0;
    #pragma unroll
    for (int i = 1; i < 13; i++) e += (eidx >= d_EOFF[i]);
    int li = eidx - d_EOFF[e];
    int dst = ep.p[e][d_ECNT[e] + li];
    atomicAdd(&cnt[d_NOFF[d_EDT[e]] + dst], 1);
}

__global__ void k_scan_a(const int* __restrict__ cnt, int* __restrict__ partial) {
    __shared__ int s[256];
    int i = blockIdx.x * 256 + threadIdx.x;
    s[threadIdx.x] = (i < NTOT) ? cnt[i] : 0;
    __syncthreads();
    for (int off = 128; off > 0; off >>= 1) {
        if (threadIdx.x < off) s[threadIdx.x] += s[threadIdx.x + off];
        __syncthreads();
    }
    if (threadIdx.x == 0) partial[blockIdx.x] = s[0];
}

__global__ void k_scan_b(int* __restrict__ partial, int nblk) {
    __shared__ int s[512];
    int t = threadIdx.x;
    s[t] = (t < nblk) ? partial[t] : 0;
    __syncthreads();
    for (int off = 1; off < 512; off <<= 1) {
        int v = (t >= off) ? s[t - off] : 0;
        __syncthreads();
        s[t] += v;
        __syncthreads();
    }
    if (t < nblk) partial[t] = t ? s[t - 1] : 0;   // exclusive
}

__global__ void k_scan_c(const int* __restrict__ cnt, const int* __restrict__ partial,
                         int* __restrict__ row_ptr) {
    __shared__ int s[256];
    int i = blockIdx.x * 256 + threadIdx.x, t = threadIdx.x;
    int v = (i < NTOT) ? cnt[i] : 0;
    s[t] = v;
    __syncthreads();
    for (int off = 1; off < 256; off <<= 1) {
        int u = (t >= off) ? s[t - off] : 0;
        __syncthreads();
        s[t] += u;
        __syncthreads();
    }
    if (i < NTOT) row_ptr[i] = s[t] - v + partial[blockIdx.x];
    if (i == NTOT - 1) row_ptr[NTOT] = s[t] + partial[blockIdx.x];
}

__global__ void k_fill(EdgePtrs ep, const int* __restrict__ row_ptr,
                       int* __restrict__ cursor, int* __restrict__ csr) {
    int eidx = blockIdx.x * blockDim.x + threadIdx.x;
    if (eidx >= ETOT) return;
    int e = 0;
    #pragma unroll
    for (int i = 1; i < 13; i++) e += (eidx >= d_EOFF[i]);
    int li = eidx - d_EOFF[e];
    const int* base = ep.p[e];
    int src = base[li], dst = base[d_ECNT[e] + li];
    int dg = d_NOFF[d_EDT[e]] + dst;
    int pos = atomicAdd(&cursor[dg], 1);
    csr[row_ptr[dg] + pos] = d_EBASE[e] + src;
}

// ---------------- weight fusion (R13) ----------------
// Wf[e] = Wkqv_k  . blockdiag(Wk[e]) * prel*0.25   (64x64 per edge type)
// Wg[e] = Wkqv_v  . blockdiag(Wv[e])
// Column space per layer (NCOLS=1856): per type t at off {0,832,1664}:
//   cols [0,64)            : q col c        (copy of Wkqv q-part)
//   cols 64 + el*128 + l   : kt col l of local edge type el
//   cols 64 + el*128+64+ l : vt col l
// Row-major 64-float rows -> main kernel reads dwordx4 per lane.
__global__ __launch_bounds__(64)
void k_fuse(const float* __restrict__ Wkqv, const float* __restrict__ bkqv,
            const float* __restrict__ Wk, const float* __restrict__ Wv,
            const float* __restrict__ prel,
            float* __restrict__ Wcat, float* __restrict__ bcat) {
    int blk = blockIdx.x;                 // 0 .. 2*NCOLS-1
    int l = blk / NCOLS, c = blk % NCOLS;
    int t = (c < 832) ? 0 : (c < 1664) ? 1 : 2;
    int tc = c - ((t == 0) ? 0 : (t == 1) ? 832 : 1664);
    int i = threadIdx.x;                  // input dim 0..63
    const float* Wsrc = Wkqv + (size_t)(l * 3 + t) * 64 * 192;
    const float* bsrc = bkqv + (l * 3 + t) * 192;
    float wval, bval = 0.f;
    if (tc < 64) {                        // q column
        wval = Wsrc[i * 192 + 64 + tc];
        bval = bsrc[64 + tc];
    } else {
        int idx = tc - 64, el = idx >> 7, r = idx & 127;
        int isv = r >> 6, lcol = r & 63, hh = lcol >> 4, xo = lcol & 15;
        int e0 = (t == 0) ? 0 : (t == 1) ? 6 : 12;
        int e = e0 + el;
        const float* M = (isv ? Wv : Wk) + (((size_t)(l * 13 + e)) * 4 + hh) * 256 + xo;
        float pr = isv ? 1.f : prel[(l * 13 + e) * 4 + hh] * 0.25f;
        int kc = (isv ? 128 : 0) + hh * 16;   // kqv col base (k: 0..63, v: 128..191)
        float s = 0.f;
        #pragma unroll
        for (int d = 0; d < 16; d++) s += Wsrc[i * 192 + kc + d] * M[d * 16];
        wval = s * pr;
        if (i == 0) {
            float sb = 0.f;
            #pragma unroll
            for (int d = 0; d < 16; d++) sb += bsrc[kc + d] * M[d * 16];
            bval = sb * pr;
        }
    }
    Wcat[((size_t)l * NCOLS + c) * 64 + i] = wval;
    if (i == 0) bcat[l * NCOLS + c] = bval;
}

// ---------------- fused q + kvt via pre-fused weights (R13) ----------------
// 512 threads, 16 nodes/block. Thread u owns one output unit:
//   u < 64          : q column u        (one K=64 dot per node)
//   u in [64, U(t)) : kvt lane pair     (kt_l, vt_l) of local edge (u-64)>>6
// h read as block-uniform s_load_dwordx4; W per-lane dwordx4; i-parity pk_fma
// with the s-pair trick (R12). No LDS, no barriers, no DS reads.
__global__ __launch_bounds__(512)
void k_kqvt(const float* __restrict__ h, const float* __restrict__ Wcat,
            const float* __restrict__ bcat,
            float* __restrict__ qagg, __half2* __restrict__ kvt, int layer) {
    int n0 = blockIdx.x * 16;
    int t = node_type(n0);          // 16-node tiles never straddle type boundaries
    int U = (t == 2) ? 128 : 448;
    int u = threadIdx.x;
    if (u >= U) return;
    int nn = min(16, NTOT - n0);
    const float* hb = h + (size_t)n0 * 64;
    int coff = (t == 0) ? 0 : (t == 1) ? 832 : 1664;
    size_t lbase = (size_t)layer * NCOLS;

    if (u < 64) {
        // ---- q column u
        const float* Wq = Wcat + (lbase + coff + u) * 64;
        float bq = bcat[lbase + coff + u];
        f32x2 acc[16];
        #pragma unroll
        for (int n = 0; n < 16; n++) { acc[n].x = bq; acc[n].y = 0.f; }
        #pragma unroll
        for (int ic = 0; ic < 16; ic++) {
            float4 w4 = *(const float4*)(Wq + ic * 4);
            f32x2 wA; wA.x = w4.x; wA.y = w4.y;
            f32x2 wB; wB.x = w4.z; wB.y = w4.w;
            #pragma unroll
            for (int n = 0; n < 16; n++) {
                float4 hv = *(const float4*)(hb + n * 64 + ic * 4);  // uniform
                f32x2 p0; p0.x = hv.x; p0.y = hv.y; pk_fma_sv(acc[n], p0, wA);
                f32x2 p1; p1.x = hv.z; p1.y = hv.w; pk_fma_sv(acc[n], p1, wB);
            }
        }
        #pragma unroll
        for (int n = 0; n < 16; n++)
            if (n < nn) qagg[(size_t)(n0 + n) * 64 + u] = acc[n].x + acc[n].y;
    } else {
        // ---- kvt lane pair: local edge el, lane lcol
        int idx = u - 64, el = idx >> 6, lcol = idx & 63;
        int e0 = (t == 0) ? 0 : (t == 1) ? 6 : 12;
        int e = e0 + el;
        int ckt = coff + 64 + el * 128 + lcol;
        const float* Wkt = Wcat + (lbase + ckt) * 64;
        const float* Wvt = Wkt + 64 * 64;            // vt col = ckt + 64
        float bk = bcat[lbase + ckt], bv = bcat[lbase + ckt + 64];
        f32x2 ak[16], av[16];
        #pragma unroll
        for (int n = 0; n < 16; n++) {
            ak[n].x = bk; ak[n].y = 0.f;
            av[n].x = bv; av[n].y = 0.f;
        }
        #pragma unroll
        for (int ic = 0; ic < 16; ic++) {
            float4 wk4 = *(const float4*)(Wkt + ic * 4);
            float4 wv4 = *(const float4*)(Wvt + ic * 4);
            f32x2 kA; kA.x = wk4.x; kA.y = wk4.y;
            f32x2 kB; kB.x = wk4.z; kB.y = wk4.w;
            f32x2 vA; vA.x = wv4.x; vA.y = wv4.y;
            f32x2 vB; vB.x = wv4.z; vB.y = wv4.w;
            #pragma unroll
            for (int n = 0; n < 16; n++) {
                float4 hv = *(const float4*)(hb + n * 64 + ic * 4);  // uniform
                f32x2 p0; p0.x = hv.x; p0.y = hv.y;
                f32x2 p1; p1.x = hv.z; p1.y = hv.w;
                pk_fma_sv(ak[n], p0, kA);
                pk_fma_sv(ak[n], p1, kB);
                pk_fma_sv(av[n], p0, vA);
                pk_fma_sv(av[n], p1, vB);
            }
        }
        int sb = d_EBASE[e] + (n0 - d_NOFF[t]);
        #pragma unroll
        for (int n = 0; n < 16; n++)
            if (n < nn)
                kvt[(size_t)(sb + n) * 64 + lcol] =
                    __float22half2_rn(make_float2(ak[n].x + ak[n].y,
                                                  av[n].x + av[n].y));
    }
}

// -------- fused gather: score + online softmax + message agg --------
__device__ __forceinline__ float row_sum16(float x) {
    int v;
    v = __builtin_amdgcn_update_dpp(0, __float_as_int(x), 0xB1, 0xF, 0xF, true); // quad_perm [1,0,3,2] : xor1
    x += __int_as_float(v);
    v = __builtin_amdgcn_update_dpp(0, __float_as_int(x), 0x4E, 0xF, 0xF, true); // quad_perm [2,3,0,1] : xor2
    x += __int_as_float(v);
    v = __builtin_amdgcn_update_dpp(0, __float_as_int(x), 0x141, 0xF, 0xF, true); // row_half_mirror : xor4
    x += __int_as_float(v);
    v = __builtin_amdgcn_update_dpp(0, __float_as_int(x), 0x140, 0xF, 0xF, true); // row_mirror : xor8
    x += __int_as_float(v);
    return x;
}

__device__ __forceinline__ void osm_step(float s, float vv,
                                         float& m, float& l, float& acc) {
    float d = s - m;
    float t = __expf(-fabsf(d));    // one exp per edge
    bool pos = d > 0.f;
    m = fmaxf(m, s);
    float sc = pos ? t : 1.f;
    float es = pos ? 1.f : t;
    l   = l * sc + es;
    acc = acc * sc + es * vv;
}

__global__ __launch_bounds__(512, 8)
void k_gather(float* __restrict__ qagg, const __half2* __restrict__ kvt,
              const int* __restrict__ row_ptr, const int* __restrict__ csr) {
    int wave = threadIdx.x >> 6, lane = threadIdx.x & 63;
    int node = blockIdx.x * 8 + wave;
    if (node >= NTOT) return;
    float q = qagg[(size_t)node * 64 + lane];   // q[h][x]
    int beg = row_ptr[node], end = row_ptr[node + 1];
    float m0 = -1e30f, l0 = 0.f, a0 = 0.f;      // even-edge chain
    float m1 = -1e30f, l1 = 0.f, a1 = 0.f;      // odd-edge chain
    for (int base = beg; base < end; base += 64) {
        int n = end - base; if (n > 64) n = 64;
        int ent = csr[base + ((lane < n) ? lane : 0)];   // 64 entries in one load
        for (int c = 0; c < n; c += 8) {
            int cn = n - c; if (cn > 8) cn = 8;
            __half2 f[8];
            #pragma unroll
            for (int k = 0; k < 8; k++) {               // batch 8 gathers (MLP)
                int idx = c + ((k < cn) ? k : 0);
                int sl = __shfl(ent, idx, 64);
                f[k] = kvt[(size_t)sl * 64 + lane];
            }
            float s8[8];
            #pragma unroll
            for (int k = 0; k < 8; k++) {               // 8 independent reductions
                if (k >= cn) break;                     // uniform branch
                s8[k] = row_sum16(q * __low2float(f[k]));
            }
            #pragma unroll
            for (int k = 0; k < 8; k += 2) {            // 2 interleaved chains
                if (k < cn)     osm_step(s8[k],   __high2float(f[k]),   m0, l0, a0);
                if (k + 1 < cn) osm_step(s8[k+1], __high2float(f[k+1]), m1, l1, a1);
            }
        }
    }
    // merge the two online-softmax states
    float M   = fmaxf(m0, m1);
    float e0  = __expf(m0 - M), e1 = __expf(m1 - M);
    float l   = l0 * e0 + l1 * e1;
    float acc = a0 * e0 + a1 * e1;
    qagg[(size_t)node * 64 + lane] = (l > 0.f) ? acc / l : 0.f;
}

// ------- epilogue: gelu -> @Wout + bout -> skip-gate -> relu [-> l2norm on last]
__global__ __launch_bounds__(256)
void k_out(const float* __restrict__ agg, const float* __restrict__ Wout,
           const float* __restrict__ bout, const float* __restrict__ skip,
           float* __restrict__ h, float* __restrict__ out, int layer, int last) {
    int b = blockIdx.x; int t, n0, lim;
    if (b < 938)       { t = 0; n0 = b * 32;                 lim = NU; }
    else if (b < 2813) { t = 1; n0 = NU + (b - 938) * 32;    lim = NU + NE_; }
    else               { t = 2; n0 = NU + NE_ + (b - 2813) * 32; lim = NTOT; }
    int nn = min(32, lim - n0);
    __shared__ float gsT[64][36];   // transposed gelu tile: gsT[col][node], padded
    for (int i = threadIdx.x; i < nn * 64; i += 256) {
        float o = agg[(size_t)n0 * 64 + i];
        gsT[i & 63][i >> 6] = 0.5f * o * (1.f + erff(o * 0.70710678118654752f));
    }
    __syncthreads();
    int j = threadIdx.x & 63, g = threadIdx.x >> 6;   // 4 waves x 8 nodes
    const float* W = Wout + (size_t)(layer * 3 + t) * HID * HID;
    float bb = bout[(layer * 3 + t) * HID + j];
    f32x2 acc2[4];
    #pragma unroll
    for (int p = 0; p < 4; p++) { acc2[p].x = bb; acc2[p].y = bb; }
    for (int i = 0; i < 64; i++) {
        float w = W[i * 64 + j];
        f32x2 w2; w2.x = w; w2.y = w;
        float4 a = *(const float4*)(&gsT[i][g * 8]);       // nodes 0..3 (broadcast)
        float4 c = *(const float4*)(&gsT[i][g * 8 + 4]);   // nodes 4..7 (broadcast)
        f32x2 p0; p0.x = a.x; p0.y = a.y; pk_fma(acc2[0], p0, w2);
        f32x2 p1; p1.x = a.z; p1.y = a.w; pk_fma(acc2[1], p1, w2);
        f32x2 p2; p2.x = c.x; p2.y = c.y; pk_fma(acc2[2], p2, w2);
        f32x2 p3; p3.x = c.z; p3.y = c.w; pk_fma(acc2[3], p3, w2);
    }
    float acc[8];
    #pragma unroll
    for (int p = 0; p < 4; p++) { acc[2 * p] = acc2[p].x; acc[2 * p + 1] = acc2[p].y; }
    float gk = 1.f / (1.f + __expf(-skip[layer * 3 + t]));
    #pragma unroll
    for (int n = 0; n < 8; n++) {
        int node = n0 + g * 8 + n;
        if (node >= lim) continue;
        float r = gk * acc[n] + (1.f - gk) * h[(size_t)node * 64 + j];
        r = fmaxf(r, 0.f);                              // relu
        if (!last) {
            h[(size_t)node * 64 + j] = r;
        } else {                                        // fused l2 normalize
            float ss = r * r;
            ss += __shfl_xor(ss, 1, 64);  ss += __shfl_xor(ss, 2, 64);
            ss += __shfl_xor(ss, 4, 64);  ss += __shfl_xor(ss, 8, 64);
            ss += __shfl_xor(ss, 16, 64); ss += __shfl_xor(ss, 32, 64);
            float nrm = fmaxf(sqrtf(ss), 1e-12f);
            out[(size_t)node * 64 + j] = r / nrm;
        }
    }
}

extern "C" void kernel_launch(void* const* d_in, const int* in_sizes, int n_in,
                              void* d_out, int out_size, void* d_ws, size_t ws_size,
                              hipStream_t stream) {
    const float* xu   = (const float*)d_in[0];
    const float* xe   = (const float*)d_in[1];
    const float* xv   = (const float*)d_in[2];
    const float* Wu   = (const float*)d_in[3];
    const float* bu   = (const float*)d_in[4];
    const float* We   = (const float*)d_in[5];
    const float* be   = (const float*)d_in[6];
    const float* Wv_  = (const float*)d_in[7];
    const float* bv   = (const float*)d_in[8];
    const float* embu = (const float*)d_in[9];
    const float* embe = (const float*)d_in[10];
    const float* embv = (const float*)d_in[11];
    const float* Wkqv = (const float*)d_in[12];
    const float* bkqv = (const float*)d_in[13];
    const float* Wk   = (const float*)d_in[14];
    const float* Wv   = (const float*)d_in[15];
    const float* prel = (const float*)d_in[16];
    const float* Wout = (const float*)d_in[17];
    const float* bout = (const float*)d_in[18];
    const float* skip = (const float*)d_in[19];
    const int*   idu  = (const int*)d_in[20];
    const int*   ide  = (const int*)d_in[21];
    const int*   idv  = (const int*)d_in[22];
    EdgePtrs ep;
    for (int e = 0; e < 13; e++) ep.p[e] = (const int*)d_in[23 + e];

    float* ws  = (float*)d_ws;
    float* h      = ws;                                    // NTOT*64 f32
    float* qagg   = h    + (size_t)NTOT * HID;             // NTOT*64 f32 (q, then agg)
    __half2* kvt  = (__half2*)(qagg + (size_t)NTOT * HID); // NSLOT*64 half2
    int* cnt     = (int*)(kvt + (size_t)NSLOT * HID);      // NTOT
    int* cursor  = cnt + NTOT;                             // NTOT
    int* row_ptr = cursor + NTOT;                          // NTOT+1
    int* partial = row_ptr + NTOT + 1;                     // 512
    int* csr     = partial + 512;                          // ETOT int
    float* Wcat  = (float*)(csr + ETOT);                   // 2*NCOLS*64 f32
    float* bcat  = Wcat + (size_t)2 * NCOLS * 64;          // 2*NCOLS f32

    k_init<<<(NTOT + 15) / 16, 64, 0, stream>>>(
        xu, xe, xv, Wu, bu, We, be, Wv_, bv, embu, embe, embv, idu, ide, idv, h);

    // fused per-edge-type weights (both layers, one dispatch)
    k_fuse<<<2 * NCOLS, 64, 0, stream>>>(Wkqv, bkqv, Wk, Wv, prel, Wcat, bcat);

    // CSR build (edges are layer-invariant); exact rows, entry = slot id
    hipMemsetAsync(cnt, 0, (size_t)2 * NTOT * 4, stream);   // cnt + cursor
    int nblk = (NTOT + 255) / 256;   // 356
    k_cnt<<<(ETOT + 255) / 256, 256, 0, stream>>>(ep, cnt);
    k_scan_a<<<nblk, 256, 0, stream>>>(cnt, partial);
    k_scan_b<<<1, 512, 0, stream>>>(partial, nblk);
    k_scan_c<<<nblk, 256, 0, stream>>>(cnt, partial, row_ptr);
    k_fill<<<(ETOT + 255) / 256, 256, 0, stream>>>(ep, row_ptr, cursor, csr);

    for (int l = 0; l < LAYERS; l++) {
        k_kqvt<<<(NTOT + 15) / 16, 512, 0, stream>>>(h, Wcat, bcat, qagg, kvt, l);
        k_gather<<<(NTOT + 7) / 8, 512, 0, stream>>>(qagg, kvt, row_ptr, csr);
        k_out<<<2845, 256, 0, stream>>>(qagg, Wout, bout, skip, h,
                                        (float*)d_out, l, l == LAYERS - 1);
    }
}

// Round 8
// 641.244 us; speedup vs baseline: 1.4593x; 1.4593x over previous
//
#include <hip/hip_runtime.h>
#include <hip/hip_fp16.h>
#include <math.h>

#define HID   64
#define HEADS 4
#define DH    16
#define NU    30000
#define NE_   60000
#define NV    1000
#define NTOT  91000
#define ETOT  870000
#define NSLOT 541000
#define LAYERS 2

// Edge-type tables
__device__ const int d_EOFF[14] = {0,150000,270000,330000,370000,400000,450000,
                                   570000,630000,670000,700000,750000,810000,870000};
__device__ const int d_ECNT[13] = {150000,120000,60000,40000,30000,50000,
                                   120000,60000,40000,30000,50000,60000,60000};
__device__ const int d_EST[13]  = {0,0,0,0,0,0,1,1,1,1,1,1,2};
__device__ const int d_EDT[13]  = {0,1,1,1,1,1,0,0,0,0,0,2,1};
__device__ const int d_NOFF[3]  = {0, NU, NU + NE_};
// slot base per edge type in the kvt mega-table (src-node indexed per e)
__device__ const int d_EBASE[13] = {0,30000,60000,90000,120000,150000,
                                    180000,240000,300000,360000,420000,480000,540000};

struct EdgePtrs { const int* p[13]; };

typedef float f32x2 __attribute__((ext_vector_type(2)));

__device__ __forceinline__ void pk_fma(f32x2& acc, f32x2 a, f32x2 b) {
    asm("v_pk_fma_f32 %0, %1, %2, %0" : "+v"(acc) : "v"(a), "v"(b));
}
// a is wave-uniform (SGPR pair) -> VOP3P scalar source, no v_mov marshalling.
__device__ __forceinline__ void pk_fma_sv(f32x2& acc, f32x2 a_sgpr, f32x2 b) {
    asm("v_pk_fma_f32 %0, %1, %2, %0" : "+v"(acc) : "s"(a_sgpr), "v"(b));
}

__device__ __forceinline__ int node_type(int n) {
    return (n >= NU) + (n >= NU + NE_);
}

// ---------------- input projection: h = x@W + b + emb[ids] ----------------
__global__ __launch_bounds__(64)
void k_init(const float* __restrict__ xu, const float* __restrict__ xe,
            const float* __restrict__ xv,
            const float* __restrict__ Wu, const float* __restrict__ bu,
            const float* __restrict__ We, const float* __restrict__ be,
            const float* __restrict__ Wv_, const float* __restrict__ bv,
            const float* __restrict__ embu, const float* __restrict__ embe,
            const float* __restrict__ embv,
            const int* __restrict__ idu, const int* __restrict__ ide,
            const int* __restrict__ idv,
            float* __restrict__ h) {
    int n0 = blockIdx.x * 16;
    int t = node_type(n0);          // 16-node tiles never straddle type boundaries
    int j = threadIdx.x;            // output column 0..63
    const float *x, *W, *bb, *emb; const int* ids; int in_dim;
    if (t == 0)      { x = xu; W = Wu;  bb = bu; emb = embu; ids = idu; in_dim = 32; }
    else if (t == 1) { x = xe; W = We;  bb = be; emb = embe; ids = ide; in_dim = 32; }
    else             { x = xv; W = Wv_; bb = bv; emb = embv; ids = idv; in_dim = 16; }
    int nl = n0 - d_NOFF[t];
    int nn = min(16, NTOT - n0);
    __shared__ float xT[32][20];    // transposed x tile, +4 pad
    int ncs = (in_dim == 32) ? 3 : 2;       // log2 float4-chunks per node
    int nch = 1 << ncs;
    for (int idx = j; idx < (nch << 4); idx += 64) {
        int n = idx >> ncs, c = idx & (nch - 1);
        float4 v = make_float4(0.f, 0.f, 0.f, 0.f);
        if (n < nn) v = *(const float4*)(x + (size_t)(nl + n) * in_dim + c * 4);
        xT[c * 4 + 0][n] = v.x;
        xT[c * 4 + 1][n] = v.y;
        xT[c * 4 + 2][n] = v.z;
        xT[c * 4 + 3][n] = v.w;
    }
    __syncthreads();
    float bj = bb[j];
    f32x2 acc2[8];
    #pragma unroll
    for (int p = 0; p < 8; p++) {
        float ex = (2 * p     < nn) ? emb[(size_t)ids[nl + 2 * p    ] * 64 + j] : 0.f;
        float ey = (2 * p + 1 < nn) ? emb[(size_t)ids[nl + 2 * p + 1] * 64 + j] : 0.f;
        acc2[p].x = bj + ex; acc2[p].y = bj + ey;
    }
    if (in_dim == 32) {
        #pragma unroll
        for (int i = 0; i < 32; i++) {
            float w = W[i * 64 + j];
            f32x2 w2; w2.x = w; w2.y = w;
            #pragma unroll
            for (int qd = 0; qd < 4; qd++) {
                float4 hv = *(const float4*)(&xT[i][qd * 4]);
                f32x2 p0; p0.x = hv.x; p0.y = hv.y; pk_fma(acc2[2 * qd],     p0, w2);
                f32x2 p1; p1.x = hv.z; p1.y = hv.w; pk_fma(acc2[2 * qd + 1], p1, w2);
            }
        }
    } else {
        #pragma unroll
        for (int i = 0; i < 16; i++) {
            float w = W[i * 64 + j];
            f32x2 w2; w2.x = w; w2.y = w;
            #pragma unroll
            for (int qd = 0; qd < 4; qd++) {
                float4 hv = *(const float4*)(&xT[i][qd * 4]);
                f32x2 p0; p0.x = hv.x; p0.y = hv.y; pk_fma(acc2[2 * qd],     p0, w2);
                f32x2 p1; p1.x = hv.z; p1.y = hv.w; pk_fma(acc2[2 * qd + 1], p1, w2);
            }
        }
    }
    #pragma unroll
    for (int p = 0; p < 8; p++) {
        if (2 * p     < nn) h[(size_t)(n0 + 2 * p)     * 64 + j] = acc2[p].x;
        if (2 * p + 1 < nn) h[(size_t)(n0 + 2 * p + 1) * 64 + j] = acc2[p].y;
    }
}

// ---------------- CSR build (exact rows, entry = slot index) ----------------
__global__ void k_cnt(EdgePtrs ep, int* __restrict__ cnt) {
    int eidx = blockIdx.x * blockDim.x + threadIdx.x;
    if (eidx >= ETOT) return;
    int e = 0;
    #pragma unroll
    for (int i = 1; i < 13; i++) e += (eidx >= d_EOFF[i]);
    int li = eidx - d_EOFF[e];
    int dst = ep.p[e][d_ECNT[e] + li];
    atomicAdd(&cnt[d_NOFF[d_EDT[e]] + dst], 1);
}

__global__ void k_scan_a(const int* __restrict__ cnt, int* __restrict__ partial) {
    __shared__ int s[256];
    int i = blockIdx.x * 256 + threadIdx.x;
    s[threadIdx.x] = (i < NTOT) ? cnt[i] : 0;
    __syncthreads();
    for (int off = 128; off > 0; off >>= 1) {
        if (threadIdx.x < off) s[threadIdx.x] += s[threadIdx.x + off];
        __syncthreads();
    }
    if (threadIdx.x == 0) partial[blockIdx.x] = s[0];
}

__global__ void k_scan_b(int* __restrict__ partial, int nblk) {
    __shared__ int s[512];
    int t = threadIdx.x;
    s[t] = (t < nblk) ? partial[t] : 0;
    __syncthreads();
    for (int off = 1; off < 512; off <<= 1) {
        int v = (t >= off) ? s[t - off] : 0;
        __syncthreads();
        s[t] += v;
        __syncthreads();
    }
    if (t < nblk) partial[t] = t ? s[t - 1] : 0;   // exclusive
}

__global__ void k_scan_c(const int* __restrict__ cnt, const int* __restrict__ partial,
                         int* __restrict__ row_ptr) {
    __shared__ int s[256];
    int i = blockIdx.x * 256 + threadIdx.x, t = threadIdx.x;
    int v = (i < NTOT) ? cnt[i] : 0;
    s[t] = v;
    __syncthreads();
    for (int off = 1; off < 256; off <<= 1) {
        int u = (t >= off) ? s[t - off] : 0;
        __syncthreads();
        s[t] += u;
        __syncthreads();
    }
    if (i < NTOT) row_ptr[i] = s[t] - v + partial[blockIdx.x];
    if (i == NTOT - 1) row_ptr[NTOT] = s[t] + partial[blockIdx.x];
}

__global__ void k_fill(EdgePtrs ep, const int* __restrict__ row_ptr,
                       int* __restrict__ cursor, int* __restrict__ csr) {
    int eidx = blockIdx.x * blockDim.x + threadIdx.x;
    if (eidx >= ETOT) return;
    int e = 0;
    #pragma unroll
    for (int i = 1; i < 13; i++) e += (eidx >= d_EOFF[i]);
    int li = eidx - d_EOFF[e];
    const int* base = ep.p[e];
    int src = base[li], dst = base[d_ECNT[e] + li];
    int dg = d_NOFF[d_EDT[e]] + dst;
    int pos = atomicAdd(&cursor[dg], 1);
    csr[row_ptr[dg] + pos] = d_EBASE[e] + src;
}

// ---------------- fused kqv projection + kvt slot table build ----------------
// R12 structure (best known: 95.7us). Stage 1: uniform global h reads + s-pair
// pk_fma; stage 2: reg-cached weights + broadcast LDS reads. R13's fused-W
// variant regressed to 275us (per-lane W streaming = latency-bound) - reverted.
__global__ __launch_bounds__(192, 3)
void k_kqvt(const float* __restrict__ h, const float* __restrict__ Wkqv,
            const float* __restrict__ bkqv, const float* __restrict__ Wk,
            const float* __restrict__ Wv, const float* __restrict__ prel,
            float* __restrict__ qagg, __half2* __restrict__ kvt, int layer) {
    int n0 = blockIdx.x * 16;
    int t = node_type(n0);          // 16-node tiles never straddle type boundaries
    __shared__ float kq[16][192];   // per node: k 0..63 | q 64..127 | v 128..191
    int j = threadIdx.x;

    // ---- stage 1: column j of kqv for 16 nodes; uniform global h reads
    const float* hb = h + (size_t)n0 * 64;
    const float* Wc = Wkqv + (size_t)(layer * 3 + t) * HID * 192 + j;
    float b = bkqv[(layer * 3 + t) * 192 + j];
    f32x2 acc2[16];
    #pragma unroll
    for (int n = 0; n < 16; n++) { acc2[n].x = 0.f; acc2[n].y = 0.f; }
    #pragma unroll
    for (int ic = 0; ic < 16; ic++) {
        float w0 = Wc[(size_t)(4 * ic + 0) * 192];
        float w1 = Wc[(size_t)(4 * ic + 1) * 192];
        float w2 = Wc[(size_t)(4 * ic + 2) * 192];
        float w3 = Wc[(size_t)(4 * ic + 3) * 192];
        f32x2 wA; wA.x = w0; wA.y = w1;
        f32x2 wB; wB.x = w2; wB.y = w3;
        #pragma unroll
        for (int n = 0; n < 16; n++) {
            float4 hv = *(const float4*)(hb + n * 64 + ic * 4);  // block-uniform
            f32x2 p0; p0.x = hv.x; p0.y = hv.y;
            pk_fma_sv(acc2[n], p0, wA);
            f32x2 p1; p1.x = hv.z; p1.y = hv.w;
            pk_fma_sv(acc2[n], p1, wB);
        }
    }
    float accf[16];
    #pragma unroll
    for (int n = 0; n < 16; n++) accf[n] = b + acc2[n].x + acc2[n].y;
    #pragma unroll
    for (int n = 0; n < 16; n++) kq[n][j] = accf[n];
    if (j >= 64 && j < 128) {
        #pragma unroll
        for (int n = 0; n < 16; n++)
            if (n0 + n < NTOT) qagg[(size_t)(n0 + n) * 64 + (j - 64)] = accf[n];
    }
    __syncthreads();

    // ---- stage 2: emit kvt slots for the edge types sourced by this node type
    int wave = j >> 6, lane = j & 63;
    int hh = lane >> 4, xo = lane & 15;
    int ne = (t == 2) ? 1 : 6;
    int e0 = (t == 0) ? 0 : (t == 1) ? 6 : 12;
    int eA = e0 + wave, eB = e0 + wave + 3;
    bool vA = wave < ne, vB = wave + 3 < ne;
    int nt = n0 - d_NOFF[t];
    f32x2 wkA[8], wvA[8], wkB[8], wvB[8];
    int sbA = 0, sbB = 0;
    if (vA) {
        const float* Wkp = Wk + (((size_t)layer * 13 + eA) * 4 + hh) * 256 + xo;
        const float* Wvp = Wv + (((size_t)layer * 13 + eA) * 4 + hh) * 256 + xo;
        float pr = prel[(layer * 13 + eA) * 4 + hh] * 0.25f;
        #pragma unroll
        for (int p = 0; p < 8; p++) {
            wkA[p].x = Wkp[(2 * p)     * 16] * pr;
            wkA[p].y = Wkp[(2 * p + 1) * 16] * pr;
            wvA[p].x = Wvp[(2 * p)     * 16];
            wvA[p].y = Wvp[(2 * p + 1) * 16];
        }
        sbA = d_EBASE[eA] + nt;
    }
    if (vB) {
        const float* Wkp = Wk + (((size_t)layer * 13 + eB) * 4 + hh) * 256 + xo;
        const float* Wvp = Wv + (((size_t)layer * 13 + eB) * 4 + hh) * 256 + xo;
        float pr = prel[(layer * 13 + eB) * 4 + hh] * 0.25f;
        #pragma unroll
        for (int p = 0; p < 8; p++) {
            wkB[p].x = Wkp[(2 * p)     * 16] * pr;
            wkB[p].y = Wkp[(2 * p + 1) * 16] * pr;
            wvB[p].x = Wvp[(2 * p)     * 16];
            wvB[p].y = Wvp[(2 * p + 1) * 16];
        }
        sbB = d_EBASE[eB] + nt;
    }
    #pragma unroll
    for (int n = 0; n < 16; n++) {
        bool ok = (n0 + n) < NTOT;                 // uniform; false only in tail tile
        const float* kr = &kq[n][hh * 16];
        const float* vr = &kq[n][128 + hh * 16];
        float4 k0 = ((const float4*)kr)[0];
        float4 k1 = ((const float4*)kr)[1];
        float4 k2 = ((const float4*)kr)[2];
        float4 k3 = ((const float4*)kr)[3];
        float4 v0 = ((const float4*)vr)[0];
        float4 v1 = ((const float4*)vr)[1];
        float4 v2 = ((const float4*)vr)[2];
        float4 v3 = ((const float4*)vr)[3];
        if (vA & ok) {
            f32x2 ak; ak.x = 0.f; ak.y = 0.f;
            f32x2 av; av.x = 0.f; av.y = 0.f;
            f32x2 p0;
            p0.x = k0.x; p0.y = k0.y; pk_fma(ak, p0, wkA[0]);
            p0.x = k0.z; p0.y = k0.w; pk_fma(ak, p0, wkA[1]);
            p0.x = k1.x; p0.y = k1.y; pk_fma(ak, p0, wkA[2]);
            p0.x = k1.z; p0.y = k1.w; pk_fma(ak, p0, wkA[3]);
            p0.x = k2.x; p0.y = k2.y; pk_fma(ak, p0, wkA[4]);
            p0.x = k2.z; p0.y = k2.w; pk_fma(ak, p0, wkA[5]);
            p0.x = k3.x; p0.y = k3.y; pk_fma(ak, p0, wkA[6]);
            p0.x = k3.z; p0.y = k3.w; pk_fma(ak, p0, wkA[7]);
            p0.x = v0.x; p0.y = v0.y; pk_fma(av, p0, wvA[0]);
            p0.x = v0.z; p0.y = v0.w; pk_fma(av, p0, wvA[1]);
            p0.x = v1.x; p0.y = v1.y; pk_fma(av, p0, wvA[2]);
            p0.x = v1.z; p0.y = v1.w; pk_fma(av, p0, wvA[3]);
            p0.x = v2.x; p0.y = v2.y; pk_fma(av, p0, wvA[4]);
            p0.x = v2.z; p0.y = v2.w; pk_fma(av, p0, wvA[5]);
            p0.x = v3.x; p0.y = v3.y; pk_fma(av, p0, wvA[6]);
            p0.x = v3.z; p0.y = v3.w; pk_fma(av, p0, wvA[7]);
            float kt = ak.x + ak.y;
            float vt = av.x + av.y;
            kvt[(size_t)(sbA + n) * 64 + lane] = __float22half2_rn(make_float2(kt, vt));
        }
        if (vB & ok) {
            f32x2 ak; ak.x = 0.f; ak.y = 0.f;
            f32x2 av; av.x = 0.f; av.y = 0.f;
            f32x2 p0;
            p0.x = k0.x; p0.y = k0.y; pk_fma(ak, p0, wkB[0]);
            p0.x = k0.z; p0.y = k0.w; pk_fma(ak, p0, wkB[1]);
            p0.x = k1.x; p0.y = k1.y; pk_fma(ak, p0, wkB[2]);
            p0.x = k1.z; p0.y = k1.w; pk_fma(ak, p0, wkB[3]);
            p0.x = k2.x; p0.y = k2.y; pk_fma(ak, p0, wkB[4]);
            p0.x = k2.z; p0.y = k2.w; pk_fma(ak, p0, wkB[5]);
            p0.x = k3.x; p0.y = k3.y; pk_fma(ak, p0, wkB[6]);
            p0.x = k3.z; p0.y = k3.w; pk_fma(ak, p0, wkB[7]);
            p0.x = v0.x; p0.y = v0.y; pk_fma(av, p0, wvB[0]);
            p0.x = v0.z; p0.y = v0.w; pk_fma(av, p0, wvB[1]);
            p0.x = v1.x; p0.y = v1.y; pk_fma(av, p0, wvB[2]);
            p0.x = v1.z; p0.y = v1.w; pk_fma(av, p0, wvB[3]);
            p0.x = v2.x; p0.y = v2.y; pk_fma(av, p0, wvB[4]);
            p0.x = v2.z; p0.y = v2.w; pk_fma(av, p0, wvB[5]);
            p0.x = v3.x; p0.y = v3.y; pk_fma(av, p0, wvB[6]);
            p0.x = v3.z; p0.y = v3.w; pk_fma(av, p0, wvB[7]);
            float kt = ak.x + ak.y;
            float vt = av.x + av.y;
            kvt[(size_t)(sbB + n) * 64 + lane] = __float22half2_rn(make_float2(kt, vt));
        }
    }
}

// -------- fused gather: score + online softmax + message agg --------
// R14: (a) slot broadcast via v_readlane (uniform index) instead of
//      ds_bpermute -- removes 8 DS ops/batch and puts the gather address in
//      SGPR (saddr form); (b) double-buffered 8-edge batches (fA/fB, named
//      swap) so the next batch's 8 loads are in flight under the current
//      batch's DPP-reduce + osm chain. Edge order unchanged -> bitwise-same.
__device__ __forceinline__ float row_sum16(float x) {
    int v;
    v = __builtin_amdgcn_update_dpp(0, __float_as_int(x), 0xB1, 0xF, 0xF, true); // quad_perm [1,0,3,2] : xor1
    x += __int_as_float(v);
    v = __builtin_amdgcn_update_dpp(0, __float_as_int(x), 0x4E, 0xF, 0xF, true); // quad_perm [2,3,0,1] : xor2
    x += __int_as_float(v);
    v = __builtin_amdgcn_update_dpp(0, __float_as_int(x), 0x141, 0xF, 0xF, true); // row_half_mirror : xor4
    x += __int_as_float(v);
    v = __builtin_amdgcn_update_dpp(0, __float_as_int(x), 0x140, 0xF, 0xF, true); // row_mirror : xor8
    x += __int_as_float(v);
    return x;
}

__device__ __forceinline__ void osm_step(float s, float vv,
                                         float& m, float& l, float& acc) {
    float d = s - m;
    float t = __expf(-fabsf(d));    // one exp per edge
    bool pos = d > 0.f;
    m = fmaxf(m, s);
    float sc = pos ? t : 1.f;
    float es = pos ? 1.f : t;
    l   = l * sc + es;
    acc = acc * sc + es * vv;
}

__device__ __forceinline__ void load8(__half2* f, const __half2* __restrict__ kvt,
                                      int ent, int lane, int c0, int n) {
    int cnl = n - c0; if (cnl > 8) cnl = 8;
    #pragma unroll
    for (int k = 0; k < 8; k++) {
        int idx = c0 + ((k < cnl) ? k : 0);          // wave-uniform
        int sl = __builtin_amdgcn_readlane(ent, idx);// SGPR slot id
        f[k] = kvt[(size_t)sl * 64 + lane];
    }
}

__device__ __forceinline__ void proc8(const __half2* f, int cn, float q,
                                      float& m0, float& l0, float& a0,
                                      float& m1, float& l1, float& a1) {
    float s8[8];
    #pragma unroll
    for (int k = 0; k < 8; k++) {                    // 8 independent reductions
        if (k >= cn) break;                          // uniform branch
        s8[k] = row_sum16(q * __low2float(f[k]));
    }
    #pragma unroll
    for (int k = 0; k < 8; k += 2) {                 // 2 interleaved chains
        if (k < cn)     osm_step(s8[k],   __high2float(f[k]),   m0, l0, a0);
        if (k + 1 < cn) osm_step(s8[k+1], __high2float(f[k+1]), m1, l1, a1);
    }
}

__global__ __launch_bounds__(512, 8)
void k_gather(float* __restrict__ qagg, const __half2* __restrict__ kvt,
              const int* __restrict__ row_ptr, const int* __restrict__ csr) {
    int wave = threadIdx.x >> 6, lane = threadIdx.x & 63;
    int node = blockIdx.x * 8 + wave;
    if (node >= NTOT) return;
    float q = qagg[(size_t)node * 64 + lane];   // q[h][x]
    int beg = row_ptr[node], end = row_ptr[node + 1];
    float m0 = -1e30f, l0 = 0.f, a0 = 0.f;      // even-edge chain
    float m1 = -1e30f, l1 = 0.f, a1 = 0.f;      // odd-edge chain
    for (int base = beg; base < end; base += 64) {
        int n = end - base; if (n > 64) n = 64;
        int ent = csr[base + ((lane < n) ? lane : 0)];   // 64 entries in one load
        __half2 fA[8], fB[8];
        load8(fA, kvt, ent, lane, 0, n);
        int c = 0;
        while (true) {
            if (c + 8 < n) load8(fB, kvt, ent, lane, c + 8, n);   // prefetch
            int cn = n - c; if (cn > 8) cn = 8;
            proc8(fA, cn, q, m0, l0, a0, m1, l1, a1);
            c += 8;
            if (c >= n) break;
            if (c + 8 < n) load8(fA, kvt, ent, lane, c + 8, n);   // prefetch
            cn = n - c; if (cn > 8) cn = 8;
            proc8(fB, cn, q, m0, l0, a0, m1, l1, a1);
            c += 8;
            if (c >= n) break;
        }
    }
    // merge the two online-softmax states
    float M   = fmaxf(m0, m1);
    float e0  = __expf(m0 - M), e1 = __expf(m1 - M);
    float l   = l0 * e0 + l1 * e1;
    float acc = a0 * e0 + a1 * e1;
    qagg[(size_t)node * 64 + lane] = (l > 0.f) ? acc / l : 0.f;
}

// ------- epilogue: gelu -> @Wout + bout -> skip-gate -> relu [-> l2norm on last]
__global__ __launch_bounds__(256)
void k_out(const float* __restrict__ agg, const float* __restrict__ Wout,
           const float* __restrict__ bout, const float* __restrict__ skip,
           float* __restrict__ h, float* __restrict__ out, int layer, int last) {
    int b = blockIdx.x; int t, n0, lim;
    if (b < 938)       { t = 0; n0 = b * 32;                 lim = NU; }
    else if (b < 2813) { t = 1; n0 = NU + (b - 938) * 32;    lim = NU + NE_; }
    else               { t = 2; n0 = NU + NE_ + (b - 2813) * 32; lim = NTOT; }
    int nn = min(32, lim - n0);
    __shared__ float gsT[64][36];   // transposed gelu tile: gsT[col][node], padded
    for (int i = threadIdx.x; i < nn * 64; i += 256) {
        float o = agg[(size_t)n0 * 64 + i];
        gsT[i & 63][i >> 6] = 0.5f * o * (1.f + erff(o * 0.70710678118654752f));
    }
    __syncthreads();
    int j = threadIdx.x & 63, g = threadIdx.x >> 6;   // 4 waves x 8 nodes
    const float* W = Wout + (size_t)(layer * 3 + t) * HID * HID;
    float bb = bout[(layer * 3 + t) * HID + j];
    f32x2 acc2[4];
    #pragma unroll
    for (int p = 0; p < 4; p++) { acc2[p].x = bb; acc2[p].y = bb; }
    for (int i = 0; i < 64; i++) {
        float w = W[i * 64 + j];
        f32x2 w2; w2.x = w; w2.y = w;
        float4 a = *(const float4*)(&gsT[i][g * 8]);       // nodes 0..3 (broadcast)
        float4 c = *(const float4*)(&gsT[i][g * 8 + 4]);   // nodes 4..7 (broadcast)
        f32x2 p0; p0.x = a.x; p0.y = a.y; pk_fma(acc2[0], p0, w2);
        f32x2 p1; p1.x = a.z; p1.y = a.w; pk_fma(acc2[1], p1, w2);
        f32x2 p2; p2.x = c.x; p2.y = c.y; pk_fma(acc2[2], p2, w2);
        f32x2 p3; p3.x = c.z; p3.y = c.w; pk_fma(acc2[3], p3, w2);
    }
    float acc[8];
    #pragma unroll
    for (int p = 0; p < 4; p++) { acc[2 * p] = acc2[p].x; acc[2 * p + 1] = acc2[p].y; }
    float gk = 1.f / (1.f + __expf(-skip[layer * 3 + t]));
    #pragma unroll
    for (int n = 0; n < 8; n++) {
        int node = n0 + g * 8 + n;
        if (node >= lim) continue;
        float r = gk * acc[n] + (1.f - gk) * h[(size_t)node * 64 + j];
        r = fmaxf(r, 0.f);                              // relu
        if (!last) {
            h[(size_t)node * 64 + j] = r;
        } else {                                        // fused l2 normalize
            float ss = r * r;
            ss += __shfl_xor(ss, 1, 64);  ss += __shfl_xor(ss, 2, 64);
            ss += __shfl_xor(ss, 4, 64);  ss += __shfl_xor(ss, 8, 64);
            ss += __shfl_xor(ss, 16, 64); ss += __shfl_xor(ss, 32, 64);
            float nrm = fmaxf(sqrtf(ss), 1e-12f);
            out[(size_t)node * 64 + j] = r / nrm;
        }
    }
}

extern "C" void kernel_launch(void* const* d_in, const int* in_sizes, int n_in,
                              void* d_out, int out_size, void* d_ws, size_t ws_size,
                              hipStream_t stream) {
    const float* xu   = (const float*)d_in[0];
    const float* xe   = (const float*)d_in[1];
    const float* xv   = (const float*)d_in[2];
    const float* Wu   = (const float*)d_in[3];
    const float* bu   = (const float*)d_in[4];
    const float* We   = (const float*)d_in[5];
    const float* be   = (const float*)d_in[6];
    const float* Wv_  = (const float*)d_in[7];
    const float* bv   = (const float*)d_in[8];
    const float* embu = (const float*)d_in[9];
    const float* embe = (const float*)d_in[10];
    const float* embv = (const float*)d_in[11];
    const float* Wkqv = (const float*)d_in[12];
    const float* bkqv = (const float*)d_in[13];
    const float* Wk   = (const float*)d_in[14];
    const float* Wv   = (const float*)d_in[15];
    const float* prel = (const float*)d_in[16];
    const float* Wout = (const float*)d_in[17];
    const float* bout = (const float*)d_in[18];
    const float* skip = (const float*)d_in[19];
    const int*   idu  = (const int*)d_in[20];
    const int*   ide  = (const int*)d_in[21];
    const int*   idv  = (const int*)d_in[22];
    EdgePtrs ep;
    for (int e = 0; e < 13; e++) ep.p[e] = (const int*)d_in[23 + e];

    float* ws  = (float*)d_ws;
    float* h      = ws;                                    // NTOT*64 f32
    float* qagg   = h    + (size_t)NTOT * HID;             // NTOT*64 f32 (q, then agg)
    __half2* kvt  = (__half2*)(qagg + (size_t)NTOT * HID); // NSLOT*64 half2
    int* cnt     = (int*)(kvt + (size_t)NSLOT * HID);      // NTOT
    int* cursor  = cnt + NTOT;                             // NTOT
    int* row_ptr = cursor + NTOT;                          // NTOT+1
    int* partial = row_ptr + NTOT + 1;                     // 512
    int* csr     = partial + 512;                          // ETOT int

    k_init<<<(NTOT + 15) / 16, 64, 0, stream>>>(
        xu, xe, xv, Wu, bu, We, be, Wv_, bv, embu, embe, embv, idu, ide, idv, h);

    // CSR build (edges are layer-invariant); exact rows, entry = slot id
    hipMemsetAsync(cnt, 0, (size_t)2 * NTOT * 4, stream);   // cnt + cursor
    int nblk = (NTOT + 255) / 256;   // 356
    k_cnt<<<(ETOT + 255) / 256, 256, 0, stream>>>(ep, cnt);
    k_scan_a<<<nblk, 256, 0, stream>>>(cnt, partial);
    k_scan_b<<<1, 512, 0, stream>>>(partial, nblk);
    k_scan_c<<<nblk, 256, 0, stream>>>(cnt, partial, row_ptr);
    k_fill<<<(ETOT + 255) / 256, 256, 0, stream>>>(ep, row_ptr, cursor, csr);

    for (int l = 0; l < LAYERS; l++) {
        k_kqvt<<<(NTOT + 15) / 16, 192, 0, stream>>>(h, Wkqv, bkqv, Wk, Wv, prel,
                                                     qagg, kvt, l);
        k_gather<<<(NTOT + 7) / 8, 512, 0, stream>>>(qagg, kvt, row_ptr, csr);
        k_out<<<2845, 256, 0, stream>>>(qagg, Wout, bout, skip, h,
                                        (float*)d_out, l, l == LAYERS - 1);
    }
}

// Round 9
// 598.926 us; speedup vs baseline: 1.5624x; 1.0707x over previous
//
#include <hip/hip_runtime.h>
#include <hip/hip_fp16.h>
#include <math.h>

#define HID   64
#define HEADS 4
#define DH    16
#define NU    30000
#define NE_   60000
#define NV    1000
#define NTOT  91000
#define ETOT  870000
#define NSLOT 541000
#define LAYERS 2

// Edge-type tables
__device__ const int d_EOFF[14] = {0,150000,270000,330000,370000,400000,450000,
                                   570000,630000,670000,700000,750000,810000,870000};
__device__ const int d_ECNT[13] = {150000,120000,60000,40000,30000,50000,
                                   120000,60000,40000,30000,50000,60000,60000};
__device__ const int d_EST[13]  = {0,0,0,0,0,0,1,1,1,1,1,1,2};
__device__ const int d_EDT[13]  = {0,1,1,1,1,1,0,0,0,0,0,2,1};
__device__ const int d_NOFF[3]  = {0, NU, NU + NE_};
// slot base per edge type in the kvt mega-table (src-node indexed per e)
__device__ const int d_EBASE[13] = {0,30000,60000,90000,120000,150000,
                                    180000,240000,300000,360000,420000,480000,540000};

struct EdgePtrs { const int* p[13]; };

typedef float f32x2 __attribute__((ext_vector_type(2)));

__device__ __forceinline__ void pk_fma(f32x2& acc, f32x2 a, f32x2 b) {
    asm("v_pk_fma_f32 %0, %1, %2, %0" : "+v"(acc) : "v"(a), "v"(b));
}
// a is wave-uniform (SGPR pair) -> VOP3P scalar source, no v_mov marshalling.
__device__ __forceinline__ void pk_fma_sv(f32x2& acc, f32x2 a_sgpr, f32x2 b) {
    asm("v_pk_fma_f32 %0, %1, %2, %0" : "+v"(acc) : "s"(a_sgpr), "v"(b));
}

__device__ __forceinline__ int node_type(int n) {
    return (n >= NU) + (n >= NU + NE_);
}

// ---------------- input projection: h = x@W + b + emb[ids] ----------------
__global__ __launch_bounds__(64)
void k_init(const float* __restrict__ xu, const float* __restrict__ xe,
            const float* __restrict__ xv,
            const float* __restrict__ Wu, const float* __restrict__ bu,
            const float* __restrict__ We, const float* __restrict__ be,
            const float* __restrict__ Wv_, const float* __restrict__ bv,
            const float* __restrict__ embu, const float* __restrict__ embe,
            const float* __restrict__ embv,
            const int* __restrict__ idu, const int* __restrict__ ide,
            const int* __restrict__ idv,
            float* __restrict__ h) {
    int n0 = blockIdx.x * 16;
    int t = node_type(n0);          // 16-node tiles never straddle type boundaries
    int j = threadIdx.x;            // output column 0..63
    const float *x, *W, *bb, *emb; const int* ids; int in_dim;
    if (t == 0)      { x = xu; W = Wu;  bb = bu; emb = embu; ids = idu; in_dim = 32; }
    else if (t == 1) { x = xe; W = We;  bb = be; emb = embe; ids = ide; in_dim = 32; }
    else             { x = xv; W = Wv_; bb = bv; emb = embv; ids = idv; in_dim = 16; }
    int nl = n0 - d_NOFF[t];
    int nn = min(16, NTOT - n0);
    __shared__ float xT[32][20];    // transposed x tile, +4 pad
    int ncs = (in_dim == 32) ? 3 : 2;       // log2 float4-chunks per node
    int nch = 1 << ncs;
    for (int idx = j; idx < (nch << 4); idx += 64) {
        int n = idx >> ncs, c = idx & (nch - 1);
        float4 v = make_float4(0.f, 0.f, 0.f, 0.f);
        if (n < nn) v = *(const float4*)(x + (size_t)(nl + n) * in_dim + c * 4);
        xT[c * 4 + 0][n] = v.x;
        xT[c * 4 + 1][n] = v.y;
        xT[c * 4 + 2][n] = v.z;
        xT[c * 4 + 3][n] = v.w;
    }
    __syncthreads();
    float bj = bb[j];
    f32x2 acc2[8];
    #pragma unroll
    for (int p = 0; p < 8; p++) {
        float ex = (2 * p     < nn) ? emb[(size_t)ids[nl + 2 * p    ] * 64 + j] : 0.f;
        float ey = (2 * p + 1 < nn) ? emb[(size_t)ids[nl + 2 * p + 1] * 64 + j] : 0.f;
        acc2[p].x = bj + ex; acc2[p].y = bj + ey;
    }
    if (in_dim == 32) {
        #pragma unroll
        for (int i = 0; i < 32; i++) {
            float w = W[i * 64 + j];
            f32x2 w2; w2.x = w; w2.y = w;
            #pragma unroll
            for (int qd = 0; qd < 4; qd++) {
                float4 hv = *(const float4*)(&xT[i][qd * 4]);
                f32x2 p0; p0.x = hv.x; p0.y = hv.y; pk_fma(acc2[2 * qd],     p0, w2);
                f32x2 p1; p1.x = hv.z; p1.y = hv.w; pk_fma(acc2[2 * qd + 1], p1, w2);
            }
        }
    } else {
        #pragma unroll
        for (int i = 0; i < 16; i++) {
            float w = W[i * 64 + j];
            f32x2 w2; w2.x = w; w2.y = w;
            #pragma unroll
            for (int qd = 0; qd < 4; qd++) {
                float4 hv = *(const float4*)(&xT[i][qd * 4]);
                f32x2 p0; p0.x = hv.x; p0.y = hv.y; pk_fma(acc2[2 * qd],     p0, w2);
                f32x2 p1; p1.x = hv.z; p1.y = hv.w; pk_fma(acc2[2 * qd + 1], p1, w2);
            }
        }
    }
    #pragma unroll
    for (int p = 0; p < 8; p++) {
        if (2 * p     < nn) h[(size_t)(n0 + 2 * p)     * 64 + j] = acc2[p].x;
        if (2 * p + 1 < nn) h[(size_t)(n0 + 2 * p + 1) * 64 + j] = acc2[p].y;
    }
}

// ---------------- CSR build (R15: single-atomic-pass) ----------------
// k_cnt's atomicAdd already yields the within-row position; record it so
// k_fill becomes a pure streaming write (no cursor atomics, no cursor memset).
__global__ void k_cnt(EdgePtrs ep, int* __restrict__ cnt, int* __restrict__ pos) {
    int eidx = blockIdx.x * blockDim.x + threadIdx.x;
    if (eidx >= ETOT) return;
    int e = 0;
    #pragma unroll
    for (int i = 1; i < 13; i++) e += (eidx >= d_EOFF[i]);
    int li = eidx - d_EOFF[e];
    int dst = ep.p[e][d_ECNT[e] + li];
    pos[eidx] = atomicAdd(&cnt[d_NOFF[d_EDT[e]] + dst], 1);
}

__global__ void k_scan_a(const int* __restrict__ cnt, int* __restrict__ partial) {
    __shared__ int s[256];
    int i = blockIdx.x * 256 + threadIdx.x;
    s[threadIdx.x] = (i < NTOT) ? cnt[i] : 0;
    __syncthreads();
    for (int off = 128; off > 0; off >>= 1) {
        if (threadIdx.x < off) s[threadIdx.x] += s[threadIdx.x + off];
        __syncthreads();
    }
    if (threadIdx.x == 0) partial[blockIdx.x] = s[0];
}

__global__ void k_scan_b(int* __restrict__ partial, int nblk) {
    __shared__ int s[512];
    int t = threadIdx.x;
    s[t] = (t < nblk) ? partial[t] : 0;
    __syncthreads();
    for (int off = 1; off < 512; off <<= 1) {
        int v = (t >= off) ? s[t - off] : 0;
        __syncthreads();
        s[t] += v;
        __syncthreads();
    }
    if (t < nblk) partial[t] = t ? s[t - 1] : 0;   // exclusive
}

__global__ void k_scan_c(const int* __restrict__ cnt, const int* __restrict__ partial,
                         int* __restrict__ row_ptr) {
    __shared__ int s[256];
    int i = blockIdx.x * 256 + threadIdx.x, t = threadIdx.x;
    int v = (i < NTOT) ? cnt[i] : 0;
    s[t] = v;
    __syncthreads();
    for (int off = 1; off < 256; off <<= 1) {
        int u = (t >= off) ? s[t - off] : 0;
        __syncthreads();
        s[t] += u;
        __syncthreads();
    }
    if (i < NTOT) row_ptr[i] = s[t] - v + partial[blockIdx.x];
    if (i == NTOT - 1) row_ptr[NTOT] = s[t] + partial[blockIdx.x];
}

__global__ void k_fill(EdgePtrs ep, const int* __restrict__ row_ptr,
                       const int* __restrict__ pos, int* __restrict__ csr) {
    int eidx = blockIdx.x * blockDim.x + threadIdx.x;
    if (eidx >= ETOT) return;
    int e = 0;
    #pragma unroll
    for (int i = 1; i < 13; i++) e += (eidx >= d_EOFF[i]);
    int li = eidx - d_EOFF[e];
    const int* base = ep.p[e];
    int src = base[li], dst = base[d_ECNT[e] + li];
    int dg = d_NOFF[d_EDT[e]] + dst;
    csr[row_ptr[dg] + pos[eidx]] = d_EBASE[e] + src;   // no atomic
}

// ---------------- fused kqv projection + kvt slot table build ----------------
// R12 structure (best known: 95.5us, VALU+DS co-bound).
__global__ __launch_bounds__(192, 3)
void k_kqvt(const float* __restrict__ h, const float* __restrict__ Wkqv,
            const float* __restrict__ bkqv, const float* __restrict__ Wk,
            const float* __restrict__ Wv, const float* __restrict__ prel,
            float* __restrict__ qagg, __half2* __restrict__ kvt, int layer) {
    int n0 = blockIdx.x * 16;
    int t = node_type(n0);          // 16-node tiles never straddle type boundaries
    __shared__ float kq[16][192];   // per node: k 0..63 | q 64..127 | v 128..191
    int j = threadIdx.x;

    // ---- stage 1: column j of kqv for 16 nodes; uniform global h reads
    const float* hb = h + (size_t)n0 * 64;
    const float* Wc = Wkqv + (size_t)(layer * 3 + t) * HID * 192 + j;
    float b = bkqv[(layer * 3 + t) * 192 + j];
    f32x2 acc2[16];
    #pragma unroll
    for (int n = 0; n < 16; n++) { acc2[n].x = 0.f; acc2[n].y = 0.f; }
    #pragma unroll
    for (int ic = 0; ic < 16; ic++) {
        float w0 = Wc[(size_t)(4 * ic + 0) * 192];
        float w1 = Wc[(size_t)(4 * ic + 1) * 192];
        float w2 = Wc[(size_t)(4 * ic + 2) * 192];
        float w3 = Wc[(size_t)(4 * ic + 3) * 192];
        f32x2 wA; wA.x = w0; wA.y = w1;
        f32x2 wB; wB.x = w2; wB.y = w3;
        #pragma unroll
        for (int n = 0; n < 16; n++) {
            float4 hv = *(const float4*)(hb + n * 64 + ic * 4);  // block-uniform
            f32x2 p0; p0.x = hv.x; p0.y = hv.y;
            pk_fma_sv(acc2[n], p0, wA);
            f32x2 p1; p1.x = hv.z; p1.y = hv.w;
            pk_fma_sv(acc2[n], p1, wB);
        }
    }
    float accf[16];
    #pragma unroll
    for (int n = 0; n < 16; n++) accf[n] = b + acc2[n].x + acc2[n].y;
    #pragma unroll
    for (int n = 0; n < 16; n++) kq[n][j] = accf[n];
    if (j >= 64 && j < 128) {
        #pragma unroll
        for (int n = 0; n < 16; n++)
            if (n0 + n < NTOT) qagg[(size_t)(n0 + n) * 64 + (j - 64)] = accf[n];
    }
    __syncthreads();

    // ---- stage 2: emit kvt slots for the edge types sourced by this node type
    int wave = j >> 6, lane = j & 63;
    int hh = lane >> 4, xo = lane & 15;
    int ne = (t == 2) ? 1 : 6;
    int e0 = (t == 0) ? 0 : (t == 1) ? 6 : 12;
    int eA = e0 + wave, eB = e0 + wave + 3;
    bool vA = wave < ne, vB = wave + 3 < ne;
    int nt = n0 - d_NOFF[t];
    f32x2 wkA[8], wvA[8], wkB[8], wvB[8];
    int sbA = 0, sbB = 0;
    if (vA) {
        const float* Wkp = Wk + (((size_t)layer * 13 + eA) * 4 + hh) * 256 + xo;
        const float* Wvp = Wv + (((size_t)layer * 13 + eA) * 4 + hh) * 256 + xo;
        float pr = prel[(layer * 13 + eA) * 4 + hh] * 0.25f;
        #pragma unroll
        for (int p = 0; p < 8; p++) {
            wkA[p].x = Wkp[(2 * p)     * 16] * pr;
            wkA[p].y = Wkp[(2 * p + 1) * 16] * pr;
            wvA[p].x = Wvp[(2 * p)     * 16];
            wvA[p].y = Wvp[(2 * p + 1) * 16];
        }
        sbA = d_EBASE[eA] + nt;
    }
    if (vB) {
        const float* Wkp = Wk + (((size_t)layer * 13 + eB) * 4 + hh) * 256 + xo;
        const float* Wvp = Wv + (((size_t)layer * 13 + eB) * 4 + hh) * 256 + xo;
        float pr = prel[(layer * 13 + eB) * 4 + hh] * 0.25f;
        #pragma unroll
        for (int p = 0; p < 8; p++) {
            wkB[p].x = Wkp[(2 * p)     * 16] * pr;
            wkB[p].y = Wkp[(2 * p + 1) * 16] * pr;
            wvB[p].x = Wvp[(2 * p)     * 16];
            wvB[p].y = Wvp[(2 * p + 1) * 16];
        }
        sbB = d_EBASE[eB] + nt;
    }
    #pragma unroll
    for (int n = 0; n < 16; n++) {
        bool ok = (n0 + n) < NTOT;                 // uniform; false only in tail tile
        const float* kr = &kq[n][hh * 16];
        const float* vr = &kq[n][128 + hh * 16];
        float4 k0 = ((const float4*)kr)[0];
        float4 k1 = ((const float4*)kr)[1];
        float4 k2 = ((const float4*)kr)[2];
        float4 k3 = ((const float4*)kr)[3];
        float4 v0 = ((const float4*)vr)[0];
        float4 v1 = ((const float4*)vr)[1];
        float4 v2 = ((const float4*)vr)[2];
        float4 v3 = ((const float4*)vr)[3];
        if (vA & ok) {
            f32x2 ak; ak.x = 0.f; ak.y = 0.f;
            f32x2 av; av.x = 0.f; av.y = 0.f;
            f32x2 p0;
            p0.x = k0.x; p0.y = k0.y; pk_fma(ak, p0, wkA[0]);
            p0.x = k0.z; p0.y = k0.w; pk_fma(ak, p0, wkA[1]);
            p0.x = k1.x; p0.y = k1.y; pk_fma(ak, p0, wkA[2]);
            p0.x = k1.z; p0.y = k1.w; pk_fma(ak, p0, wkA[3]);
            p0.x = k2.x; p0.y = k2.y; pk_fma(ak, p0, wkA[4]);
            p0.x = k2.z; p0.y = k2.w; pk_fma(ak, p0, wkA[5]);
            p0.x = k3.x; p0.y = k3.y; pk_fma(ak, p0, wkA[6]);
            p0.x = k3.z; p0.y = k3.w; pk_fma(ak, p0, wkA[7]);
            p0.x = v0.x; p0.y = v0.y; pk_fma(av, p0, wvA[0]);
            p0.x = v0.z; p0.y = v0.w; pk_fma(av, p0, wvA[1]);
            p0.x = v1.x; p0.y = v1.y; pk_fma(av, p0, wvA[2]);
            p0.x = v1.z; p0.y = v1.w; pk_fma(av, p0, wvA[3]);
            p0.x = v2.x; p0.y = v2.y; pk_fma(av, p0, wvA[4]);
            p0.x = v2.z; p0.y = v2.w; pk_fma(av, p0, wvA[5]);
            p0.x = v3.x; p0.y = v3.y; pk_fma(av, p0, wvA[6]);
            p0.x = v3.z; p0.y = v3.w; pk_fma(av, p0, wvA[7]);
            float kt = ak.x + ak.y;
            float vt = av.x + av.y;
            kvt[(size_t)(sbA + n) * 64 + lane] = __float22half2_rn(make_float2(kt, vt));
        }
        if (vB & ok) {
            f32x2 ak; ak.x = 0.f; ak.y = 0.f;
            f32x2 av; av.x = 0.f; av.y = 0.f;
            f32x2 p0;
            p0.x = k0.x; p0.y = k0.y; pk_fma(ak, p0, wkB[0]);
            p0.x = k0.z; p0.y = k0.w; pk_fma(ak, p0, wkB[1]);
            p0.x = k1.x; p0.y = k1.y; pk_fma(ak, p0, wkB[2]);
            p0.x = k1.z; p0.y = k1.w; pk_fma(ak, p0, wkB[3]);
            p0.x = k2.x; p0.y = k2.y; pk_fma(ak, p0, wkB[4]);
            p0.x = k2.z; p0.y = k2.w; pk_fma(ak, p0, wkB[5]);
            p0.x = k3.x; p0.y = k3.y; pk_fma(ak, p0, wkB[6]);
            p0.x = k3.z; p0.y = k3.w; pk_fma(ak, p0, wkB[7]);
            p0.x = v0.x; p0.y = v0.y; pk_fma(av, p0, wvB[0]);
            p0.x = v0.z; p0.y = v0.w; pk_fma(av, p0, wvB[1]);
            p0.x = v1.x; p0.y = v1.y; pk_fma(av, p0, wvB[2]);
            p0.x = v1.z; p0.y = v1.w; pk_fma(av, p0, wvB[3]);
            p0.x = v2.x; p0.y = v2.y; pk_fma(av, p0, wvB[4]);
            p0.x = v2.z; p0.y = v2.w; pk_fma(av, p0, wvB[5]);
            p0.x = v3.x; p0.y = v3.y; pk_fma(av, p0, wvB[6]);
            p0.x = v3.z; p0.y = v3.w; pk_fma(av, p0, wvB[7]);
            float kt = ak.x + ak.y;
            float vt = av.x + av.y;
            kvt[(size_t)(sbB + n) * 64 + lane] = __float22half2_rn(make_float2(kt, vt));
        }
    }
}

// -------- fused gather: score + online softmax + message agg --------
// R15: loads reverted to the proven R6 shfl/single-buffer form (R14's
// readlane + manual dbuf regressed: scalar-pipe serialization + broke the
// compiler's own load batching). New: FOUR interleaved osm chains (k&3,
// constant-folded) -> dependent-chain depth per 8-edge batch drops 4 -> 2.
__device__ __forceinline__ float row_sum16(float x) {
    int v;
    v = __builtin_amdgcn_update_dpp(0, __float_as_int(x), 0xB1, 0xF, 0xF, true); // quad_perm [1,0,3,2] : xor1
    x += __int_as_float(v);
    v = __builtin_amdgcn_update_dpp(0, __float_as_int(x), 0x4E, 0xF, 0xF, true); // quad_perm [2,3,0,1] : xor2
    x += __int_as_float(v);
    v = __builtin_amdgcn_update_dpp(0, __float_as_int(x), 0x141, 0xF, 0xF, true); // row_half_mirror : xor4
    x += __int_as_float(v);
    v = __builtin_amdgcn_update_dpp(0, __float_as_int(x), 0x140, 0xF, 0xF, true); // row_mirror : xor8
    x += __int_as_float(v);
    return x;
}

__device__ __forceinline__ void osm_step(float s, float vv,
                                         float& m, float& l, float& acc) {
    float d = s - m;
    float t = __expf(-fabsf(d));    // one exp per edge
    bool pos = d > 0.f;
    m = fmaxf(m, s);
    float sc = pos ? t : 1.f;
    float es = pos ? 1.f : t;
    l   = l * sc + es;
    acc = acc * sc + es * vv;
}

__global__ __launch_bounds__(512, 8)
void k_gather(float* __restrict__ qagg, const __half2* __restrict__ kvt,
              const int* __restrict__ row_ptr, const int* __restrict__ csr) {
    int wave = threadIdx.x >> 6, lane = threadIdx.x & 63;
    int node = blockIdx.x * 8 + wave;
    if (node >= NTOT) return;
    float q = qagg[(size_t)node * 64 + lane];   // q[h][x]
    int beg = row_ptr[node], end = row_ptr[node + 1];
    float m0 = -1e30f, l0 = 0.f, a0 = 0.f;      // chain 0 (edges k%4==0)
    float m1 = -1e30f, l1 = 0.f, a1 = 0.f;      // chain 1
    float m2 = -1e30f, l2 = 0.f, a2 = 0.f;      // chain 2
    float m3 = -1e30f, l3 = 0.f, a3 = 0.f;      // chain 3
    for (int base = beg; base < end; base += 64) {
        int n = end - base; if (n > 64) n = 64;
        int ent = csr[base + ((lane < n) ? lane : 0)];   // 64 entries in one load
        for (int c = 0; c < n; c += 8) {
            int cn = n - c; if (cn > 8) cn = 8;
            __half2 f[8];
            #pragma unroll
            for (int k = 0; k < 8; k++) {               // batch 8 gathers (MLP)
                int idx = c + ((k < cn) ? k : 0);
                int sl = __shfl(ent, idx, 64);
                f[k] = kvt[(size_t)sl * 64 + lane];
            }
            float s8[8];
            #pragma unroll
            for (int k = 0; k < 8; k++) {               // 8 independent reductions
                if (k >= cn) break;                     // uniform branch
                s8[k] = row_sum16(q * __low2float(f[k]));
            }
            // 4 interleaved chains: dependent depth 2 per batch
            if (0 < cn) osm_step(s8[0], __high2float(f[0]), m0, l0, a0);
            if (1 < cn) osm_step(s8[1], __high2float(f[1]), m1, l1, a1);
            if (2 < cn) osm_step(s8[2], __high2float(f[2]), m2, l2, a2);
            if (3 < cn) osm_step(s8[3], __high2float(f[3]), m3, l3, a3);
            if (4 < cn) osm_step(s8[4], __high2float(f[4]), m0, l0, a0);
            if (5 < cn) osm_step(s8[5], __high2float(f[5]), m1, l1, a1);
            if (6 < cn) osm_step(s8[6], __high2float(f[6]), m2, l2, a2);
            if (7 < cn) osm_step(s8[7], __high2float(f[7]), m3, l3, a3);
        }
    }
    // merge the four online-softmax states
    float M   = fmaxf(fmaxf(m0, m1), fmaxf(m2, m3));
    float e0  = __expf(m0 - M), e1 = __expf(m1 - M);
    float e2  = __expf(m2 - M), e3 = __expf(m3 - M);
    float l   = l0 * e0 + l1 * e1 + l2 * e2 + l3 * e3;
    float acc = a0 * e0 + a1 * e1 + a2 * e2 + a3 * e3;
    qagg[(size_t)node * 64 + lane] = (l > 0.f) ? acc / l : 0.f;
}

// ------- epilogue: gelu -> @Wout + bout -> skip-gate -> relu [-> l2norm on last]
__global__ __launch_bounds__(256)
void k_out(const float* __restrict__ agg, const float* __restrict__ Wout,
           const float* __restrict__ bout, const float* __restrict__ skip,
           float* __restrict__ h, float* __restrict__ out, int layer, int last) {
    int b = blockIdx.x; int t, n0, lim;
    if (b < 938)       { t = 0; n0 = b * 32;                 lim = NU; }
    else if (b < 2813) { t = 1; n0 = NU + (b - 938) * 32;    lim = NU + NE_; }
    else               { t = 2; n0 = NU + NE_ + (b - 2813) * 32; lim = NTOT; }
    int nn = min(32, lim - n0);
    __shared__ float gsT[64][36];   // transposed gelu tile: gsT[col][node], padded
    for (int i = threadIdx.x; i < nn * 64; i += 256) {
        float o = agg[(size_t)n0 * 64 + i];
        gsT[i & 63][i >> 6] = 0.5f * o * (1.f + erff(o * 0.70710678118654752f));
    }
    __syncthreads();
    int j = threadIdx.x & 63, g = threadIdx.x >> 6;   // 4 waves x 8 nodes
    const float* W = Wout + (size_t)(layer * 3 + t) * HID * HID;
    float bb = bout[(layer * 3 + t) * HID + j];
    f32x2 acc2[4];
    #pragma unroll
    for (int p = 0; p < 4; p++) { acc2[p].x = bb; acc2[p].y = bb; }
    for (int i = 0; i < 64; i++) {
        float w = W[i * 64 + j];
        f32x2 w2; w2.x = w; w2.y = w;
        float4 a = *(const float4*)(&gsT[i][g * 8]);       // nodes 0..3 (broadcast)
        float4 c = *(const float4*)(&gsT[i][g * 8 + 4]);   // nodes 4..7 (broadcast)
        f32x2 p0; p0.x = a.x; p0.y = a.y; pk_fma(acc2[0], p0, w2);
        f32x2 p1; p1.x = a.z; p1.y = a.w; pk_fma(acc2[1], p1, w2);
        f32x2 p2; p2.x = c.x; p2.y = c.y; pk_fma(acc2[2], p2, w2);
        f32x2 p3; p3.x = c.z; p3.y = c.w; pk_fma(acc2[3], p3, w2);
    }
    float acc[8];
    #pragma unroll
    for (int p = 0; p < 4; p++) { acc[2 * p] = acc2[p].x; acc[2 * p + 1] = acc2[p].y; }
    float gk = 1.f / (1.f + __expf(-skip[layer * 3 + t]));
    #pragma unroll
    for (int n = 0; n < 8; n++) {
        int node = n0 + g * 8 + n;
        if (node >= lim) continue;
        float r = gk * acc[n] + (1.f - gk) * h[(size_t)node * 64 + j];
        r = fmaxf(r, 0.f);                              // relu
        if (!last) {
            h[(size_t)node * 64 + j] = r;
        } else {                                        // fused l2 normalize
            float ss = r * r;
            ss += __shfl_xor(ss, 1, 64);  ss += __shfl_xor(ss, 2, 64);
            ss += __shfl_xor(ss, 4, 64);  ss += __shfl_xor(ss, 8, 64);
            ss += __shfl_xor(ss, 16, 64); ss += __shfl_xor(ss, 32, 64);
            float nrm = fmaxf(sqrtf(ss), 1e-12f);
            out[(size_t)node * 64 + j] = r / nrm;
        }
    }
}

extern "C" void kernel_launch(void* const* d_in, const int* in_sizes, int n_in,
                              void* d_out, int out_size, void* d_ws, size_t ws_size,
                              hipStream_t stream) {
    const float* xu   = (const float*)d_in[0];
    const float* xe   = (const float*)d_in[1];
    const float* xv   = (const float*)d_in[2];
    const float* Wu   = (const float*)d_in[3];
    const float* bu   = (const float*)d_in[4];
    const float* We   = (const float*)d_in[5];
    const float* be   = (const float*)d_in[6];
    const float* Wv_  = (const float*)d_in[7];
    const float* bv   = (const float*)d_in[8];
    const float* embu = (const float*)d_in[9];
    const float* embe = (const float*)d_in[10];
    const float* embv = (const float*)d_in[11];
    const float* Wkqv = (const float*)d_in[12];
    const float* bkqv = (const float*)d_in[13];
    const float* Wk   = (const float*)d_in[14];
    const float* Wv   = (const float*)d_in[15];
    const float* prel = (const float*)d_in[16];
    const float* Wout = (const float*)d_in[17];
    const float* bout = (const float*)d_in[18];
    const float* skip = (const float*)d_in[19];
    const int*   idu  = (const int*)d_in[20];
    const int*   ide  = (const int*)d_in[21];
    const int*   idv  = (const int*)d_in[22];
    EdgePtrs ep;
    for (int e = 0; e < 13; e++) ep.p[e] = (const int*)d_in[23 + e];

    float* ws  = (float*)d_ws;
    float* h      = ws;                                    // NTOT*64 f32
    float* qagg   = h    + (size_t)NTOT * HID;             // NTOT*64 f32 (q, then agg)
    __half2* kvt  = (__half2*)(qagg + (size_t)NTOT * HID); // NSLOT*64 half2
    int* cnt     = (int*)(kvt + (size_t)NSLOT * HID);      // NTOT
    int* row_ptr = cnt + NTOT;                             // NTOT+1
    int* partial = row_ptr + NTOT + 1;                     // 512
    int* csr     = partial + 512;                          // ETOT int
    int* pos     = csr + ETOT;                             // ETOT int

    k_init<<<(NTOT + 15) / 16, 64, 0, stream>>>(
        xu, xe, xv, Wu, bu, We, be, Wv_, bv, embu, embe, embv, idu, ide, idv, h);

    // CSR build (edges are layer-invariant); exact rows, entry = slot id
    hipMemsetAsync(cnt, 0, (size_t)NTOT * 4, stream);
    int nblk = (NTOT + 255) / 256;   // 356
    k_cnt<<<(ETOT + 255) / 256, 256, 0, stream>>>(ep, cnt, pos);
    k_scan_a<<<nblk, 256, 0, stream>>>(cnt, partial);
    k_scan_b<<<1, 512, 0, stream>>>(partial, nblk);
    k_scan_c<<<nblk, 256, 0, stream>>>(cnt, partial, row_ptr);
    k_fill<<<(ETOT + 255) / 256, 256, 0, stream>>>(ep, row_ptr, pos, csr);

    for (int l = 0; l < LAYERS; l++) {
        k_kqvt<<<(NTOT + 15) / 16, 192, 0, stream>>>(h, Wkqv, bkqv, Wk, Wv, prel,
                                                     qagg, kvt, l);
        k_gather<<<(NTOT + 7) / 8, 512, 0, stream>>>(qagg, kvt, row_ptr, csr);
        k_out<<<2845, 256, 0, stream>>>(qagg, Wout, bout, skip, h,
                                        (float*)d_out, l, l == LAYERS - 1);
    }
}